// Round 9
// baseline (4613.005 us; speedup 1.0000x reference)
//
#include <hip/hip_runtime.h>
#include <hip/hip_bf16.h>
#include <stdint.h>

#define N_ATOMS 500000
#define N_MOLS  25000
#define HID     300
#define BA      256       // atoms per block
#define NTHR    1024      // threads per block (16 waves)
#define WS_ELE  102400    // elements per repacked W matrix (20*10*64*8)
#define NCH     19        // K=16 chunks covering k<304
#define AROWB   616       // A row stride in LDS bytes (308 bf16; ~2-way banks)

typedef __attribute__((ext_vector_type(8)))  short          short8v;
typedef __attribute__((ext_vector_type(16))) float          f32x16;

static __device__ __forceinline__ unsigned short f2bf(float f) {
  unsigned int u = __float_as_uint(f);
  u += 0x7fffu + ((u >> 16) & 1u);   // round-to-nearest-even
  return (unsigned short)(u >> 16);
}

// ---------------------------------------------------------------------------
// Prep: repack W1/V1 into B-fragment order [kc16:20][nt:10][lane:64][j:8]
// (k = kc16*16 + (lane>>5)*8 + j, n = nt*32 + (lane&31)), pad biases/readout
// vectors to 320, zero the segment-sum accumulators.
// ---------------------------------------------------------------------------
__global__ void prep_kernel(
    const float* __restrict__ W1, const float* __restrict__ V1,
    const float* __restrict__ b1, const float* __restrict__ vb1,
    const float* __restrict__ W2, const float* __restrict__ V2,
    unsigned short* __restrict__ W1s, unsigned short* __restrict__ V1s,
    float* __restrict__ b1p, float* __restrict__ vb1p,
    float* __restrict__ W2p, float* __restrict__ V2p,
    float* __restrict__ sums)
{
  const int t = blockIdx.x * 256 + threadIdx.x;
  if (t < 2 * WS_ELE) {
    const float* src = (t < WS_ELE) ? W1 : V1;
    unsigned short* dst = (t < WS_ELE) ? W1s : V1s;
    const int i    = (t < WS_ELE) ? t : t - WS_ELE;
    const int j    = i & 7;
    const int lane = (i >> 3) & 63;
    const int nt   = (i >> 9) % 10;
    const int kc16 = i / 5120;
    const int k = kc16 * 16 + (lane >> 5) * 8 + j;
    const int n = nt * 32 + (lane & 31);
    const float v = (k < HID && n < HID) ? src[k * HID + n] : 0.f;
    dst[i] = f2bf(v);
  } else if (t < 2 * WS_ELE + 1280) {
    const int i = t - 2 * WS_ELE;
    const int which = i / 320;
    const int e = i - which * 320;
    const float* s = (which == 0) ? b1 : (which == 1) ? vb1 : (which == 2) ? W2 : V2;
    float*       d = (which == 0) ? b1p : (which == 1) ? vb1p : (which == 2) ? W2p : V2p;
    d[e] = (e < HID) ? s[e] : 0.f;
  } else if (t < 2 * WS_ELE + 1280 + 2 * N_MOLS) {
    sums[t - (2 * WS_ELE + 1280)] = 0.f;
  }
}

// ---------------------------------------------------------------------------
// Fused FFN x2, BIG-BLOCK barrier-free variant. Block = 256 atoms, 1024 thr =
// 16 waves = {mtx:2} x {ch:2} x {rg:4}; wave = 64 atoms x 160 cols of ONE
// matrix (acc[2][5] f32x16 = 160 AGPR). Only 1954 blocks -> 7.6 serial
// blocks/CU (discriminating test: per-block overhead vs per-wave).
// A staged ONCE into LDS bf16 row-major (157.7KB, whole LDS), one barrier,
// then 19 K=16 chunks with NO sync: B from L2 into regs via 2x-unrolled
// double buffer (no reg copies), A via ds_read_b128 (~2-way banks = free).
// ---------------------------------------------------------------------------
__global__ __launch_bounds__(NTHR, 1) void fused_ffn(
    const float* __restrict__ hidden,
    const unsigned short* __restrict__ W1s, const unsigned short* __restrict__ V1s,
    const float* __restrict__ b1p, const float* __restrict__ vb1p,
    const float* __restrict__ W2p, const float* __restrict__ V2p,
    const float* __restrict__ b2, const float* __restrict__ vb2,
    float* __restrict__ outA, float* __restrict__ outW)
{
  __shared__ char ldsA[BA * AROWB];   // 157,696 B
  __shared__ float sOutA[BA];         // +1024
  __shared__ float sOutW[BA];         // +1024  -> 159,744 total

  const int tid = (int)threadIdx.x;
  const int ln  = tid & 63;
  const int wv  = tid >> 6;        // 0..15
  const int mtx = wv & 1;          // 0 = W-pass, 1 = V-pass
  const int ch  = (wv >> 1) & 1;   // col half (160 cols)
  const int rg  = wv >> 2;         // row quarter (64 atoms)
  const int l31 = ln & 31;
  const int lh  = ln >> 5;
  const long base = (long)blockIdx.x * BA;

  // wave's B stream: 160 cols of one matrix, frag-ordered, 5KB per K=16 chunk
  const char* bwave = (mtx ? (const char*)V1s : (const char*)W1s) + ch * 5120;

  // ---- issue B chunk-0 loads FIRST (complete during A staging) ----
  short8v b0[5], b1v[5];
  #pragma unroll
  for (int nt = 0; nt < 5; ++nt)
    b0[nt] = *reinterpret_cast<const short8v*>(bwave + nt * 1024 + ln * 16);

  // ---- A: stage 256 rows x 300 f32 -> bf16 LDS row-major, 2 batches ----
  // slots: i = tid + j*1024, row = i/76, c4 = i%76 (c4==75 -> zero pad);
  // 19456 slots = 19/thread exactly.
  #pragma unroll
  for (int bt = 0; bt < 2; ++bt) {
    const int nb = bt ? 9 : 10;
    float4 tmp[10];
    #pragma unroll
    for (int m = 0; m < 10; ++m) {
      if (m >= nb) break;
      const int i   = tid + (bt * 10 + m) * NTHR;
      const int row = i / 76;
      const int c4  = i - row * 76;
      float4 v = make_float4(0.f, 0.f, 0.f, 0.f);
      const long atom = base + row;
      if (c4 < 75 && atom < N_ATOMS)
        v = *reinterpret_cast<const float4*>(hidden + atom * (long)HID + c4 * 4);
      tmp[m] = v;
    }
    #pragma unroll
    for (int m = 0; m < 10; ++m) {
      if (m >= nb) break;
      const int i   = tid + (bt * 10 + m) * NTHR;
      const int row = i / 76;
      const int c4  = i - row * 76;
      ushort4 b;
      b.x = (unsigned short)__bfloat16_as_ushort(__float2bfloat16(tmp[m].x));
      b.y = (unsigned short)__bfloat16_as_ushort(__float2bfloat16(tmp[m].y));
      b.z = (unsigned short)__bfloat16_as_ushort(__float2bfloat16(tmp[m].z));
      b.w = (unsigned short)__bfloat16_as_ushort(__float2bfloat16(tmp[m].w));
      *reinterpret_cast<ushort4*>(ldsA + row * AROWB + c4 * 8) = b;
    }
  }
  __syncthreads();   // the ONLY barrier before the epilogue

  // ---- K-loop: no barriers; B double-buffered in regs (2x unroll) ----
  const char* aB0 = ldsA + (rg * 64 + l31) * AROWB + lh * 16;
  const char* aB1 = aB0 + 32 * AROWB;

  f32x16 acc[2][5] = {};

#define MFMA_CHUNK(cc, breg)                                                   \
  do {                                                                         \
    const short8v a0_ = *reinterpret_cast<const short8v*>(aB0 + (cc) * 32);    \
    const short8v a1_ = *reinterpret_cast<const short8v*>(aB1 + (cc) * 32);    \
    _Pragma("unroll")                                                          \
    for (int nt_ = 0; nt_ < 5; ++nt_) {                                        \
      acc[0][nt_] = __builtin_amdgcn_mfma_f32_32x32x16_bf16(a0_, (breg)[nt_],  \
                                                            acc[0][nt_], 0, 0, 0); \
      acc[1][nt_] = __builtin_amdgcn_mfma_f32_32x32x16_bf16(a1_, (breg)[nt_],  \
                                                            acc[1][nt_], 0, 0, 0); \
    }                                                                          \
  } while (0)

  // chunks 0..17 in pairs; b0 holds chunk 2i on entry
  #pragma unroll 1
  for (int i = 0; i < 9; ++i) {
    const int c = 2 * i;
    const char* s1 = bwave + (c + 1) * 10240;
    #pragma unroll
    for (int nt = 0; nt < 5; ++nt)
      b1v[nt] = *reinterpret_cast<const short8v*>(s1 + nt * 1024 + ln * 16);
    MFMA_CHUNK(c, b0);
    const char* s2 = bwave + (c + 2) * 10240;
    #pragma unroll
    for (int nt = 0; nt < 5; ++nt)
      b0[nt] = *reinterpret_cast<const short8v*>(s2 + nt * 1024 + ln * 16);
    MFMA_CHUNK(c + 1, b1v);
  }
  MFMA_CHUNK(18, b0);   // tail chunk
#undef MFMA_CHUNK

  // ---- epilogue: out[atom] = sum_n relu(X+b1)*W2 + b2 ----
  float bv[5], w2[5];
  const float* bbv = mtx ? vb1p : b1p;
  const float* ww2 = mtx ? V2p  : W2p;
  #pragma unroll
  for (int nt = 0; nt < 5; ++nt) {
    const int cix = ch * 160 + nt * 32 + l31;
    bv[nt] = bbv[cix];
    w2[nt] = ww2[cix];
  }
  if (tid < BA) { sOutA[tid] = 0.f; sOutW[tid] = 0.f; }
  __syncthreads();

  float* sOut = mtx ? sOutW : sOutA;
  #pragma unroll
  for (int rr = 0; rr < 2; ++rr) {
    #pragma unroll
    for (int r = 0; r < 16; ++r) {
      float s = 0.f;
      #pragma unroll
      for (int nt = 0; nt < 5; ++nt) {
        float x = fmaxf(acc[rr][nt][r] + bv[nt], 0.f);
        s = fmaf(x, w2[nt], s);
      }
      s += __shfl_xor(s, 1);
      s += __shfl_xor(s, 2);
      s += __shfl_xor(s, 4);
      s += __shfl_xor(s, 8);
      s += __shfl_xor(s, 16);
      if (l31 == 0) {
        const int row = rg * 64 + rr * 32 + (r & 3) + 8 * (r >> 2) + 4 * lh;
        atomicAdd(&sOut[row], s);
      }
    }
  }
  __syncthreads();
  if (tid < BA) {
    const long atom = base + tid;
    if (atom < N_ATOMS) {
      outA[atom] = sOutA[tid] + b2[0];
      outW[atom] = sOutW[tid] + vb2[0];
    }
  }
}

// ---------------------------------------------------------------------------
// Segment sums: sorted seg_ids, run-compress 8 atoms/thread before atomics.
// ---------------------------------------------------------------------------
__global__ void segsum_kernel(
    const float* __restrict__ outA, const float* __restrict__ outW,
    const int* __restrict__ seg,
    float* __restrict__ sum_o, float* __restrict__ sum_w)
{
  const long i0 = ((long)blockIdx.x * 256 + threadIdx.x) * 8;
  if (i0 >= N_ATOMS) return;
  const int4   s0 = *reinterpret_cast<const int4*>(seg + i0);
  const int4   s1 = *reinterpret_cast<const int4*>(seg + i0 + 4);
  const float4 o0 = *reinterpret_cast<const float4*>(outA + i0);
  const float4 o1 = *reinterpret_cast<const float4*>(outA + i0 + 4);
  const float4 w0 = *reinterpret_cast<const float4*>(outW + i0);
  const float4 w1 = *reinterpret_cast<const float4*>(outW + i0 + 4);
  const int   ss[8] = {s0.x, s0.y, s0.z, s0.w, s1.x, s1.y, s1.z, s1.w};
  const float oo[8] = {o0.x, o0.y, o0.z, o0.w, o1.x, o1.y, o1.z, o1.w};
  const float ww[8] = {w0.x, w0.y, w0.z, w0.w, w1.x, w1.y, w1.z, w1.w};
  int cur = ss[0];
  float ao = 0.f, aw = 0.f;
  #pragma unroll
  for (int j = 0; j < 8; ++j) {
    if (ss[j] != cur) {
      atomicAdd(&sum_o[cur], ao);
      atomicAdd(&sum_w[cur], aw);
      cur = ss[j]; ao = 0.f; aw = 0.f;
    }
    ao += oo[j]; aw += ww[j];
  }
  atomicAdd(&sum_o[cur], ao);
  atomicAdd(&sum_w[cur], aw);
}

// ---------------------------------------------------------------------------
// Final: out = output + weights * (0 - sum_o[seg]) / sum_w'[seg]
// ---------------------------------------------------------------------------
__global__ void final_kernel(
    const float* __restrict__ outA, const float* __restrict__ outW,
    const int* __restrict__ seg,
    const float* __restrict__ sum_o, const float* __restrict__ sum_w,
    float* __restrict__ out)
{
  const long i0 = ((long)blockIdx.x * 256 + threadIdx.x) * 4;
  if (i0 >= N_ATOMS) return;
  const int4   s4 = *reinterpret_cast<const int4*>(seg + i0);
  const float4 o4 = *reinterpret_cast<const float4*>(outA + i0);
  const float4 w4 = *reinterpret_cast<const float4*>(outW + i0);
  const int   ss[4] = {s4.x, s4.y, s4.z, s4.w};
  const float oo[4] = {o4.x, o4.y, o4.z, o4.w};
  const float ww[4] = {w4.x, w4.y, w4.z, w4.w};
  float r[4];
  #pragma unroll
  for (int j = 0; j < 4; ++j) {
    const int s = ss[j];
    float sw = sum_w[s];
    sw = (sw == 0.f) ? 1.f : sw;
    const float corr = (0.f - sum_o[s]) / sw;
    r[j] = oo[j] + ww[j] * corr;
  }
  *reinterpret_cast<float4*>(out + i0) = make_float4(r[0], r[1], r[2], r[3]);
}

// ---------------------------------------------------------------------------
extern "C" void kernel_launch(void* const* d_in, const int* in_sizes, int n_in,
                              void* d_out, int out_size, void* d_ws, size_t ws_size,
                              hipStream_t stream)
{
  const float* hidden = (const float*)d_in[0];
  const int*   seg    = (const int*)d_in[1];
  const float* W1     = (const float*)d_in[2];
  const float* b1     = (const float*)d_in[3];
  const float* W2     = (const float*)d_in[4];
  const float* b2     = (const float*)d_in[5];
  const float* V1     = (const float*)d_in[6];
  const float* vb1    = (const float*)d_in[7];
  const float* V2     = (const float*)d_in[8];
  const float* vb2    = (const float*)d_in[9];

  char* ws = (char*)d_ws;
  float*          outA  = (float*)(ws + 0);          // 2,000,000 B
  float*          outW  = (float*)(ws + 2000000);    // 2,000,000 B
  float*          sum_o = (float*)(ws + 4000000);    //   100,000 B
  float*          sum_w = (float*)(ws + 4100000);    //   100,000 B
  unsigned short* W1s   = (unsigned short*)(ws + 4200000);  // 204,800 B
  unsigned short* V1s   = (unsigned short*)(ws + 4404800);  // 204,800 B
  float*          b1p   = (float*)(ws + 4609600);    // 1,280 B
  float*          vb1p  = (float*)(ws + 4610880);
  float*          W2p   = (float*)(ws + 4612160);
  float*          V2p   = (float*)(ws + 4613440);

  prep_kernel<<<1001, 256, 0, stream>>>(W1, V1, b1, vb1, W2, V2,
                                        W1s, V1s, b1p, vb1p, W2p, V2p, sum_o);

  const int nblk = (N_ATOMS + BA - 1) / BA;   // 1954
  fused_ffn<<<nblk, NTHR, 0, stream>>>(hidden, W1s, V1s, b1p, vb1p, W2p, V2p,
                                       b2, vb2, outA, outW);

  segsum_kernel<<<(N_ATOMS / 8 + 255) / 256, 256, 0, stream>>>(outA, outW, seg,
                                                               sum_o, sum_w);

  final_kernel<<<(N_ATOMS / 4 + 255) / 256, 256, 0, stream>>>(outA, outW, seg,
                                                              sum_o, sum_w,
                                                              (float*)d_out);
}

// Round 10
// 1100.852 us; speedup vs baseline: 4.1904x; 4.1904x over previous
//
#include <hip/hip_runtime.h>
#include <hip/hip_bf16.h>
#include <stdint.h>

#define N_ATOMS 500000
#define N_MOLS  25000
#define HID     300
#define WS_ELE  102400     // elements per repacked W matrix (20*10*64*8)
#define NCH     19         // K=16 chunks covering k<304
#define TILEB   76832      // LDS bytes per A tile buffer (76,800 staged + 32 spare)
#define NTPB    8          // 64-atom tiles per block
#define NBLK    977        // 977*512 >= 500000

typedef __attribute__((ext_vector_type(8)))  short          short8v;
typedef __attribute__((ext_vector_type(16))) float          f32x16;

static __device__ __forceinline__ unsigned short f2bf(float f) {
  unsigned int u = __float_as_uint(f);
  u += 0x7fffu + ((u >> 16) & 1u);   // round-to-nearest-even
  return (unsigned short)(u >> 16);
}

// compiler lowers scalar casts to v_cvt_pk_bf16_f32
static __device__ __forceinline__ short8v pack8(float4 a, float4 b) {
  union { __hip_bfloat16 h[8]; short8v v; } u;
  u.h[0] = __float2bfloat16(a.x); u.h[1] = __float2bfloat16(a.y);
  u.h[2] = __float2bfloat16(a.z); u.h[3] = __float2bfloat16(a.w);
  u.h[4] = __float2bfloat16(b.x); u.h[5] = __float2bfloat16(b.y);
  u.h[6] = __float2bfloat16(b.z); u.h[7] = __float2bfloat16(b.w);
  return u.v;
}

// async global->LDS, 16B per lane; lds base wave-uniform.
static __device__ __forceinline__ void stage16(const char* gsrc, char* ldst, int ln) {
  __builtin_amdgcn_global_load_lds(
      (const __attribute__((address_space(1))) void*)(gsrc + ln * 16),
      (__attribute__((address_space(3))) void*)ldst, 16, 0, 0);
}

// ---------------------------------------------------------------------------
// Prep: repack W1/V1 into B-fragment order [kc16:20][nt:10][lane:64][j:8];
// pad biases/readout vectors to 320; zero segment sums AND outA/outW
// (epilogue accumulates via atomics); copy+pad the tail A tile (last 32
// atoms) into ws so staging never reads past hidden's end.
// ---------------------------------------------------------------------------
__global__ void prep_kernel(
    const float* __restrict__ hidden,
    const float* __restrict__ W1, const float* __restrict__ V1,
    const float* __restrict__ b1, const float* __restrict__ vb1,
    const float* __restrict__ W2, const float* __restrict__ V2,
    unsigned short* __restrict__ W1s, unsigned short* __restrict__ V1s,
    float* __restrict__ b1p, float* __restrict__ vb1p,
    float* __restrict__ W2p, float* __restrict__ V2p,
    float* __restrict__ sums, float* __restrict__ outAW,
    float* __restrict__ tail)
{
  const int t = blockIdx.x * 256 + threadIdx.x;
  if (t < 2 * WS_ELE) {
    const float* src = (t < WS_ELE) ? W1 : V1;
    unsigned short* dst = (t < WS_ELE) ? W1s : V1s;
    const int i    = (t < WS_ELE) ? t : t - WS_ELE;
    const int j    = i & 7;
    const int lane = (i >> 3) & 63;
    const int nt   = (i >> 9) % 10;
    const int kc16 = i / 5120;
    const int k = kc16 * 16 + (lane >> 5) * 8 + j;
    const int n = nt * 32 + (lane & 31);
    const float v = (k < HID && n < HID) ? src[k * HID + n] : 0.f;
    dst[i] = f2bf(v);
  } else if (t < 2 * WS_ELE + 1280) {
    const int i = t - 2 * WS_ELE;
    const int which = i / 320;
    const int e = i - which * 320;
    const float* s = (which == 0) ? b1 : (which == 1) ? vb1 : (which == 2) ? W2 : V2;
    float*       d = (which == 0) ? b1p : (which == 1) ? vb1p : (which == 2) ? W2p : V2p;
    d[e] = (e < HID) ? s[e] : 0.f;
  } else if (t < 2 * WS_ELE + 1280 + 2 * N_MOLS) {
    sums[t - (2 * WS_ELE + 1280)] = 0.f;
  } else if (t < 2 * WS_ELE + 1280 + 2 * N_MOLS + 2 * N_ATOMS) {
    outAW[t - (2 * WS_ELE + 1280 + 2 * N_MOLS)] = 0.f;
  } else if (t < 2 * WS_ELE + 1280 + 2 * N_MOLS + 2 * N_ATOMS + (TILEB / 4)) {
    const int i = t - (2 * WS_ELE + 1280 + 2 * N_MOLS + 2 * N_ATOMS);
    const long g = (long)(N_ATOMS - 32) * HID + i;   // 149,990,400 + i
    tail[i] = (g < (long)N_ATOMS * HID) ? hidden[g] : 0.f;
  }
}

// ---------------------------------------------------------------------------
// Fused FFN x2 with PRODUCER/CONSUMER wave split (per-wave vmcnt queues!).
// Block = 640 thr = 10 waves: waves 0-7 consumers {mtx,ch,rg}, waves 8-9
// producers. A = f32, CONTIGUOUS 76.8KB per 64-atom tile, double-buffered in
// LDS; producers stream tile t+1 via global_load_lds (their queue, their
// counted vmcnt) while consumers compute tile t (B from L2 into regs,
// depth-1; their B-waits never drain the A stream). Raw s_barrier x2/tile.
// Epilogue: relu->dot(W2)->col-reduce, accumulate to outA/outW via global
// atomicAdd (exactly 2 commutative adds per atom -> deterministic).
// ---------------------------------------------------------------------------
__global__ __launch_bounds__(640, 2) void fused_ffn(
    const float* __restrict__ hidden, const float* __restrict__ tail,
    const unsigned short* __restrict__ W1s, const unsigned short* __restrict__ V1s,
    const float* __restrict__ b1p, const float* __restrict__ vb1p,
    const float* __restrict__ W2p, const float* __restrict__ V2p,
    const float* __restrict__ b2, const float* __restrict__ vb2,
    float* __restrict__ outA, float* __restrict__ outW)
{
  __shared__ char lds[2 * TILEB];   // 153,664 B

  const int tid = (int)threadIdx.x;
  const int ln  = tid & 63;
  const int wv  = tid >> 6;           // 0..9
  const bool producer = (wv >= 8);
  const long base = (long)blockIdx.x * (64 * NTPB);

  // tiles this block runs: tb = base + 64*t, while tb < N_ATOMS
  int ntile = NTPB;
  {
    const long rem = (long)N_ATOMS - base;
    if (rem < 64 * NTPB) ntile = (int)((rem + 63) >> 6);
  }

  // ---- producer config: 75 x 1KB pieces split 38/37 ----
  const int p0 = (wv == 8) ? 0 : 38;
  const int np = (wv == 8) ? 38 : 37;

  // ---- consumer config ----
  const int mtx = wv & 1;
  const int ch  = (wv >> 1) & 1;
  const int rg  = (wv >> 2) & 1;
  const int l31 = ln & 31;
  const int lh  = ln >> 5;
  const char* bwave = (mtx ? (const char*)V1s : (const char*)W1s) + ch * 5120;

  float bv[5], w2[5];
  float biasadd = 0.f;
  float* outP = mtx ? outW : outA;
  if (!producer) {
    const float* bbv = mtx ? vb1p : b1p;
    const float* ww2 = mtx ? V2p  : W2p;
    #pragma unroll
    for (int nt = 0; nt < 5; ++nt) {
      const int cix = ch * 160 + nt * 32 + l31;
      bv[nt] = bbv[cix];
      w2[nt] = ww2[cix];
    }
    if (ch == 0) biasadd = mtx ? vb2[0] : b2[0];
  }

  // tile t source (valid only when tb < N_ATOMS)
#define TSRC(t) ((base + 64 * (t) + 64 <= (long)N_ATOMS)                       \
                   ? (const char*)(hidden + (base + 64 * (t)) * HID)           \
                   : (const char*)tail)

  // ---- prologue: producers issue A(0) ----
  if (producer) {
    const char* s = TSRC(0);
    #pragma unroll
    for (int r = 0; r < 38; ++r)
      if (r < np) stage16(s + (p0 + r) * 1024, lds + (p0 + r) * 1024, ln);
  }

  for (int t = 0; t < ntile; ++t) {
    char* cbuf = lds + (t & 1) * TILEB;
    char* nbuf = lds + ((t + 1) & 1) * TILEB;

    __builtin_amdgcn_s_barrier();          // prev tile's readers done -> restage ok
    __builtin_amdgcn_sched_barrier(0);

    if (producer) {
      if (t + 1 < ntile) {
        const char* s = TSRC(t + 1);
        #pragma unroll
        for (int r = 0; r < 38; ++r)
          if (r < np) stage16(s + (p0 + r) * 1024, nbuf + (p0 + r) * 1024, ln);
        // own A(t) done; allow only the just-issued A(t+1) outstanding
        if (wv == 8) asm volatile("s_waitcnt vmcnt(38)" ::: "memory");
        else         asm volatile("s_waitcnt vmcnt(37)" ::: "memory");
      } else {
        asm volatile("s_waitcnt vmcnt(0)" ::: "memory");
      }
    }

    __builtin_amdgcn_s_barrier();          // A(t) visible to all
    __builtin_amdgcn_sched_barrier(0);

    if (!producer) {
      // ---- compute tile t: A from LDS f32 -> bf16, B from L2 regs ----
      const char* aP = cbuf + (rg * 32 + l31) * 1200 + lh * 32;
      f32x16 acc[5] = {};
      short8v bc[5], bn[5];
      #pragma unroll
      for (int nt = 0; nt < 5; ++nt)
        bc[nt] = *reinterpret_cast<const short8v*>(bwave + nt * 1024 + ln * 16);

      for (int c = 0; c < NCH; ++c) {
        if (c < NCH - 1) {
          const char* bsrc = bwave + (c + 1) * 10240;
          #pragma unroll
          for (int nt = 0; nt < 5; ++nt)
            bn[nt] = *reinterpret_cast<const short8v*>(bsrc + nt * 1024 + ln * 16);
        }
        const float4 f0 = *reinterpret_cast<const float4*>(aP + c * 64);
        const float4 f1 = *reinterpret_cast<const float4*>(aP + c * 64 + 16);
        const short8v af = pack8(f0, f1);
        #pragma unroll
        for (int nt = 0; nt < 5; ++nt)
          acc[nt] = __builtin_amdgcn_mfma_f32_32x32x16_bf16(af, bc[nt], acc[nt], 0, 0, 0);
        if (c < NCH - 1) {
          #pragma unroll
          for (int nt = 0; nt < 5; ++nt) bc[nt] = bn[nt];
        }
      }

      // ---- epilogue: atomically add this wave's half-col sum ----
      const long tb = base + 64 * t;
      #pragma unroll
      for (int r = 0; r < 16; ++r) {
        float s = 0.f;
        #pragma unroll
        for (int nt = 0; nt < 5; ++nt) {
          float x = fmaxf(acc[nt][r] + bv[nt], 0.f);
          s = fmaf(x, w2[nt], s);
        }
        s += __shfl_xor(s, 1);
        s += __shfl_xor(s, 2);
        s += __shfl_xor(s, 4);
        s += __shfl_xor(s, 8);
        s += __shfl_xor(s, 16);
        if (l31 == 0) {
          const int row = rg * 32 + (r & 3) + 8 * (r >> 2) + 4 * lh;
          const long atom = tb + row;
          if (atom < N_ATOMS) atomicAdd(&outP[atom], s + biasadd);
        }
      }
    }
  }
#undef TSRC
}

// ---------------------------------------------------------------------------
// Segment sums: sorted seg_ids, run-compress 8 atoms/thread before atomics.
// ---------------------------------------------------------------------------
__global__ void segsum_kernel(
    const float* __restrict__ outA, const float* __restrict__ outW,
    const int* __restrict__ seg,
    float* __restrict__ sum_o, float* __restrict__ sum_w)
{
  const long i0 = ((long)blockIdx.x * 256 + threadIdx.x) * 8;
  if (i0 >= N_ATOMS) return;
  const int4   s0 = *reinterpret_cast<const int4*>(seg + i0);
  const int4   s1 = *reinterpret_cast<const int4*>(seg + i0 + 4);
  const float4 o0 = *reinterpret_cast<const float4*>(outA + i0);
  const float4 o1 = *reinterpret_cast<const float4*>(outA + i0 + 4);
  const float4 w0 = *reinterpret_cast<const float4*>(outW + i0);
  const float4 w1 = *reinterpret_cast<const float4*>(outW + i0 + 4);
  const int   ss[8] = {s0.x, s0.y, s0.z, s0.w, s1.x, s1.y, s1.z, s1.w};
  const float oo[8] = {o0.x, o0.y, o0.z, o0.w, o1.x, o1.y, o1.z, o1.w};
  const float ww[8] = {w0.x, w0.y, w0.z, w0.w, w1.x, w1.y, w1.z, w1.w};
  int cur = ss[0];
  float ao = 0.f, aw = 0.f;
  #pragma unroll
  for (int j = 0; j < 8; ++j) {
    if (ss[j] != cur) {
      atomicAdd(&sum_o[cur], ao);
      atomicAdd(&sum_w[cur], aw);
      cur = ss[j]; ao = 0.f; aw = 0.f;
    }
    ao += oo[j]; aw += ww[j];
  }
  atomicAdd(&sum_o[cur], ao);
  atomicAdd(&sum_w[cur], aw);
}

// ---------------------------------------------------------------------------
// Final: out = output + weights * (0 - sum_o[seg]) / sum_w'[seg]
// ---------------------------------------------------------------------------
__global__ void final_kernel(
    const float* __restrict__ outA, const float* __restrict__ outW,
    const int* __restrict__ seg,
    const float* __restrict__ sum_o, const float* __restrict__ sum_w,
    float* __restrict__ out)
{
  const long i0 = ((long)blockIdx.x * 256 + threadIdx.x) * 4;
  if (i0 >= N_ATOMS) return;
  const int4   s4 = *reinterpret_cast<const int4*>(seg + i0);
  const float4 o4 = *reinterpret_cast<const float4*>(outA + i0);
  const float4 w4 = *reinterpret_cast<const float4*>(outW + i0);
  const int   ss[4] = {s4.x, s4.y, s4.z, s4.w};
  const float oo[4] = {o4.x, o4.y, o4.z, o4.w};
  const float ww[4] = {w4.x, w4.y, w4.z, w4.w};
  float r[4];
  #pragma unroll
  for (int j = 0; j < 4; ++j) {
    const int s = ss[j];
    float sw = sum_w[s];
    sw = (sw == 0.f) ? 1.f : sw;
    const float corr = (0.f - sum_o[s]) / sw;
    r[j] = oo[j] + ww[j] * corr;
  }
  *reinterpret_cast<float4*>(out + i0) = make_float4(r[0], r[1], r[2], r[3]);
}

// ---------------------------------------------------------------------------
extern "C" void kernel_launch(void* const* d_in, const int* in_sizes, int n_in,
                              void* d_out, int out_size, void* d_ws, size_t ws_size,
                              hipStream_t stream)
{
  const float* hidden = (const float*)d_in[0];
  const int*   seg    = (const int*)d_in[1];
  const float* W1     = (const float*)d_in[2];
  const float* b1     = (const float*)d_in[3];
  const float* W2     = (const float*)d_in[4];
  const float* b2     = (const float*)d_in[5];
  const float* V1     = (const float*)d_in[6];
  const float* vb1    = (const float*)d_in[7];
  const float* V2     = (const float*)d_in[8];
  const float* vb2    = (const float*)d_in[9];

  char* ws = (char*)d_ws;
  float*          outA  = (float*)(ws + 0);                 // 2,000,000 B
  float*          outW  = (float*)(ws + 2000000);           // 2,000,000 B
  float*          sum_o = (float*)(ws + 4000000);           //   100,000 B
  float*          sum_w = (float*)(ws + 4100000);           //   100,000 B
  unsigned short* W1s   = (unsigned short*)(ws + 4200000);  //   204,800 B
  unsigned short* V1s   = (unsigned short*)(ws + 4404800);  //   204,800 B
  float*          b1p   = (float*)(ws + 4609600);           //     1,280 B
  float*          vb1p  = (float*)(ws + 4610880);
  float*          W2p   = (float*)(ws + 4612160);
  float*          V2p   = (float*)(ws + 4613440);
  float*          tailb = (float*)(ws + 4614720);           //    76,832 B

  // prep grid covers repack + biases + sums + outA/outW zero + tail copy
  const int prep_threads = 2 * WS_ELE + 1280 + 2 * N_MOLS + 2 * N_ATOMS + (TILEB / 4);
  prep_kernel<<<(prep_threads + 255) / 256, 256, 0, stream>>>(
      hidden, W1, V1, b1, vb1, W2, V2,
      W1s, V1s, b1p, vb1p, W2p, V2p, sum_o, outA, tailb);

  fused_ffn<<<NBLK, 640, 0, stream>>>(hidden, tailb, W1s, V1s, b1p, vb1p,
                                      W2p, V2p, b2, vb2, outA, outW);

  segsum_kernel<<<(N_ATOMS / 8 + 255) / 256, 256, 0, stream>>>(outA, outW, seg,
                                                               sum_o, sum_w);

  final_kernel<<<(N_ATOMS / 4 + 255) / 256, 256, 0, stream>>>(outA, outW, seg,
                                                              sum_o, sum_w,
                                                              (float*)d_out);
}

// Round 11
// 485.927 us; speedup vs baseline: 9.4932x; 2.2655x over previous
//
#include <hip/hip_runtime.h>
#include <hip/hip_bf16.h>
#include <stdint.h>

#define N_ATOMS 500000
#define N_MOLS  25000
#define HID     300
#define BA      128       // atoms per block
#define NTHR    1024      // 16 waves
#define WS_ELE  102400    // elements per repacked W matrix (20*10*64*8)

// LDS layout (bytes)
#define AROWB   616               // A row stride: 308 bf16; 616%128=104 -> ~2-way banks
#define A_BYTES (BA * AROWB)      // 78,848
#define B_OFF   A_BYTES
#define BUF_B   40960             // one K=32 B chunk: [mtx:2][ks:2][nt:10][lane:64][16B]

typedef __attribute__((ext_vector_type(8)))  short          short8v;
typedef __attribute__((ext_vector_type(16))) float          f32x16;

static __device__ __forceinline__ unsigned short f2bf(float f) {
  unsigned int u = __float_as_uint(f);
  u += 0x7fffu + ((u >> 16) & 1u);   // round-to-nearest-even
  return (unsigned short)(u >> 16);
}

// async global->LDS, 16B per lane; lds base wave-uniform.
static __device__ __forceinline__ void stage16(const char* gsrc, char* ldst, int ln) {
  __builtin_amdgcn_global_load_lds(
      (const __attribute__((address_space(1))) void*)(gsrc + ln * 16),
      (__attribute__((address_space(3))) void*)ldst, 16, 0, 0);
}

// ---------------------------------------------------------------------------
// Prep: repack W1/V1 into B-fragment order [kc16:20][nt:10][lane:64][j:8]
// (k = kc16*16 + (lane>>5)*8 + j, n = nt*32 + (lane&31)), pad biases/readout
// vectors to 320, zero the segment-sum accumulators.
// ---------------------------------------------------------------------------
__global__ void prep_kernel(
    const float* __restrict__ W1, const float* __restrict__ V1,
    const float* __restrict__ b1, const float* __restrict__ vb1,
    const float* __restrict__ W2, const float* __restrict__ V2,
    unsigned short* __restrict__ W1s, unsigned short* __restrict__ V1s,
    float* __restrict__ b1p, float* __restrict__ vb1p,
    float* __restrict__ W2p, float* __restrict__ V2p,
    float* __restrict__ sums)
{
  const int t = blockIdx.x * 256 + threadIdx.x;
  if (t < 2 * WS_ELE) {
    const float* src = (t < WS_ELE) ? W1 : V1;
    unsigned short* dst = (t < WS_ELE) ? W1s : V1s;
    const int i    = (t < WS_ELE) ? t : t - WS_ELE;
    const int j    = i & 7;
    const int lane = (i >> 3) & 63;
    const int nt   = (i >> 9) % 10;
    const int kc16 = i / 5120;
    const int k = kc16 * 16 + (lane >> 5) * 8 + j;
    const int n = nt * 32 + (lane & 31);
    const float v = (k < HID && n < HID) ? src[k * HID + n] : 0.f;
    dst[i] = f2bf(v);
  } else if (t < 2 * WS_ELE + 1280) {
    const int i = t - 2 * WS_ELE;
    const int which = i / 320;
    const int e = i - which * 320;
    const float* s = (which == 0) ? b1 : (which == 1) ? vb1 : (which == 2) ? W2 : V2;
    float*       d = (which == 0) ? b1p : (which == 1) ? vb1p : (which == 2) ? W2p : V2p;
    d[e] = (e < HID) ? s[e] : 0.f;
  } else if (t < 2 * WS_ELE + 1280 + 2 * N_MOLS) {
    sums[t - (2 * WS_ELE + 1280)] = 0.f;
  }
}

// ---------------------------------------------------------------------------
// Fused FFN x2, 16-WAVE low-register variant of the best (r1/r4) structure.
// Block = 128 atoms, 1024 thr = 16 waves = {mtx:2} x {ch:2} x {rg:4}; wave =
// 32 atoms x 160 cols of ONE matrix -> acc[5] f32x16 = 80 AGPR, ~110-125
// total regs/wave -> 16 waves/CU (2x the 8-wave rounds). A staged ONCE,
// coalesced f32 -> bf16 row-major LDS (616B stride, conflict-free). B = K=32
// slabs (40KB) double-buffered via global_load_lds, staged by all 16 waves
// (2-3 pieces each), one __syncthreads per chunk, 10 chunks. Fused
// relu->dot(W2)->reduce epilogue.
// ---------------------------------------------------------------------------
__global__ __launch_bounds__(NTHR) void fused_ffn(
    const float* __restrict__ hidden,
    const unsigned short* __restrict__ W1s, const unsigned short* __restrict__ V1s,
    const float* __restrict__ b1p, const float* __restrict__ vb1p,
    const float* __restrict__ W2p, const float* __restrict__ V2p,
    const float* __restrict__ b2, const float* __restrict__ vb2,
    float* __restrict__ outA, float* __restrict__ outW)
{
  __shared__ char lds[A_BYTES + 2 * BUF_B];   // 160,768 B
  __shared__ float sOutA[BA];                 // +512
  __shared__ float sOutW[BA];                 // +512  -> 161,792 total

  const int tid = (int)threadIdx.x;
  const int ln  = tid & 63;
  const int wv  = tid >> 6;        // 0..15
  const int mtx = wv & 1;          // 0 = W-pass, 1 = V-pass
  const int ch  = (wv >> 1) & 1;   // col half (160 cols)
  const int rg  = wv >> 2;         // row group (32 atoms), 0..3
  const int l31 = ln & 31;
  const int lh  = ln >> 5;
  const long base = (long)blockIdx.x * BA;

  // B-staging role: 40 x 1KB pieces over 16 waves (waves 0-7: 3, 8-15: 2).
  const int p0 = (wv < 8) ? wv * 3 : 24 + (wv - 8) * 2;
  const int np = (wv < 8) ? 3 : 2;

#define STAGE_SLAB(cc, dstbuf) do {                                            \
    _Pragma("unroll")                                                          \
    for (int r_ = 0; r_ < 3; ++r_) {                                           \
      if (r_ < np) {                                                           \
        const int p_   = p0 + r_;                                              \
        const int mp_  = p_ / 20;                                              \
        const int q_   = p_ - mp_ * 20;                                        \
        const int kk_  = q_ / 10;                                              \
        const int nt_  = q_ - kk_ * 10;                                        \
        const char* src_ = (mp_ ? (const char*)V1s : (const char*)W1s)         \
                         + ((cc) * 2 + kk_) * 10240 + nt_ * 1024;              \
        stage16(src_, (dstbuf) + p_ * 1024, ln);                               \
      }                                                                        \
    }                                                                          \
  } while (0)

  // ---- stage B slab 0 into buf 0 (issued before A loads) ----
  STAGE_SLAB(0, lds + B_OFF);

  // ---- A: 9728 float4 slots (row = i/76, c4 = i%76; c4==75 -> zero pad) ----
  // 10 slots/thread max (9.5 avg), batched: all loads, then convert+write.
  {
    float4 tmp[10];
    #pragma unroll
    for (int j = 0; j < 10; ++j) {
      const int i = tid + j * NTHR;
      float4 v = make_float4(0.f, 0.f, 0.f, 0.f);
      if (i < BA * 76) {
        const int row = i / 76;
        const int c4  = i - row * 76;
        const long atom = base + row;
        if (c4 < 75 && atom < N_ATOMS)
          v = *reinterpret_cast<const float4*>(hidden + atom * (long)HID + c4 * 4);
      }
      tmp[j] = v;
    }
    #pragma unroll
    for (int j = 0; j < 10; ++j) {
      const int i = tid + j * NTHR;
      if (i < BA * 76) {
        const int row = i / 76;
        const int c4  = i - row * 76;
        ushort4 b;
        b.x = (unsigned short)__bfloat16_as_ushort(__float2bfloat16(tmp[j].x));
        b.y = (unsigned short)__bfloat16_as_ushort(__float2bfloat16(tmp[j].y));
        b.z = (unsigned short)__bfloat16_as_ushort(__float2bfloat16(tmp[j].z));
        b.w = (unsigned short)__bfloat16_as_ushort(__float2bfloat16(tmp[j].w));
        *reinterpret_cast<ushort4*>(lds + row * AROWB + c4 * 8) = b;
      }
    }
  }
  __syncthreads();   // A staged; B slab 0 landed

  f32x16 acc[5] = {};
  const char* aBase = lds + (rg * 32 + l31) * AROWB + lh * 16;

#define DO_KS(slab, kc16) do {                                                 \
    const short8v a_ = *reinterpret_cast<const short8v*>(aBase + (kc16) * 32); \
    const char* bb_ = (slab) + mtx * 20480 + ((kc16) & 1) * 10240 + ch * 5120; \
    _Pragma("unroll")                                                          \
    for (int nt_ = 0; nt_ < 5; ++nt_) {                                        \
      const short8v bf_ = *reinterpret_cast<const short8v*>(                   \
          bb_ + nt_ * 1024 + ln * 16);                                         \
      acc[nt_] = __builtin_amdgcn_mfma_f32_32x32x16_bf16(a_, bf_, acc[nt_], 0, 0, 0); \
    }                                                                          \
  } while (0)

  // ---- main loop: chunks 0..8 (K=32 each), then chunk 9 (K=16, kc16=18) ----
  #pragma unroll 1
  for (int c = 0; c < 9; ++c) {
    const char* slab = lds + B_OFF + (c & 1) * BUF_B;
    char*       nbuf = lds + B_OFF + ((c + 1) & 1) * BUF_B;
    STAGE_SLAB(c + 1, nbuf);          // stage next slab first
    DO_KS(slab, 2 * c);
    DO_KS(slab, 2 * c + 1);
    __syncthreads();                  // next slab landed; current free
  }
  {
    const char* slab = lds + B_OFF + (9 & 1) * BUF_B;
    DO_KS(slab, 18);                  // kc16=19 is all-pad (B zeros, A OOB) -> skip
  }
#undef DO_KS
#undef STAGE_SLAB

  // ---- epilogue: out[atom] = sum_n relu(X+b1)*W2 + b2 ----
  float bv[5], w2[5];
  const float* bbv = mtx ? vb1p : b1p;
  const float* ww2 = mtx ? V2p  : W2p;
  #pragma unroll
  for (int nt = 0; nt < 5; ++nt) {
    const int cix = ch * 160 + nt * 32 + l31;
    bv[nt] = bbv[cix];
    w2[nt] = ww2[cix];
  }
  if (tid < BA) { sOutA[tid] = 0.f; sOutW[tid] = 0.f; }
  __syncthreads();

  float* sOut = mtx ? sOutW : sOutA;
  #pragma unroll
  for (int r = 0; r < 16; ++r) {
    float s = 0.f;
    #pragma unroll
    for (int nt = 0; nt < 5; ++nt) {
      float x = fmaxf(acc[nt][r] + bv[nt], 0.f);
      s = fmaf(x, w2[nt], s);
    }
    s += __shfl_xor(s, 1);
    s += __shfl_xor(s, 2);
    s += __shfl_xor(s, 4);
    s += __shfl_xor(s, 8);
    s += __shfl_xor(s, 16);
    if (l31 == 0) {
      const int row = rg * 32 + (r & 3) + 8 * (r >> 2) + 4 * lh;
      atomicAdd(&sOut[row], s);
    }
  }
  __syncthreads();
  if (tid < BA) {
    const long atom = base + tid;
    if (atom < N_ATOMS) {
      outA[atom] = sOutA[tid] + b2[0];
      outW[atom] = sOutW[tid] + vb2[0];
    }
  }
}

// ---------------------------------------------------------------------------
// Segment sums: sorted seg_ids, run-compress 8 atoms/thread before atomics.
// ---------------------------------------------------------------------------
__global__ void segsum_kernel(
    const float* __restrict__ outA, const float* __restrict__ outW,
    const int* __restrict__ seg,
    float* __restrict__ sum_o, float* __restrict__ sum_w)
{
  const long i0 = ((long)blockIdx.x * 256 + threadIdx.x) * 8;
  if (i0 >= N_ATOMS) return;
  const int4   s0 = *reinterpret_cast<const int4*>(seg + i0);
  const int4   s1 = *reinterpret_cast<const int4*>(seg + i0 + 4);
  const float4 o0 = *reinterpret_cast<const float4*>(outA + i0);
  const float4 o1 = *reinterpret_cast<const float4*>(outA + i0 + 4);
  const float4 w0 = *reinterpret_cast<const float4*>(outW + i0);
  const float4 w1 = *reinterpret_cast<const float4*>(outW + i0 + 4);
  const int   ss[8] = {s0.x, s0.y, s0.z, s0.w, s1.x, s1.y, s1.z, s1.w};
  const float oo[8] = {o0.x, o0.y, o0.z, o0.w, o1.x, o1.y, o1.z, o1.w};
  const float ww[8] = {w0.x, w0.y, w0.z, w0.w, w1.x, w1.y, w1.z, w1.w};
  int cur = ss[0];
  float ao = 0.f, aw = 0.f;
  #pragma unroll
  for (int j = 0; j < 8; ++j) {
    if (ss[j] != cur) {
      atomicAdd(&sum_o[cur], ao);
      atomicAdd(&sum_w[cur], aw);
      cur = ss[j]; ao = 0.f; aw = 0.f;
    }
    ao += oo[j]; aw += ww[j];
  }
  atomicAdd(&sum_o[cur], ao);
  atomicAdd(&sum_w[cur], aw);
}

// ---------------------------------------------------------------------------
// Final: out = output + weights * (0 - sum_o[seg]) / sum_w'[seg]
// ---------------------------------------------------------------------------
__global__ void final_kernel(
    const float* __restrict__ outA, const float* __restrict__ outW,
    const int* __restrict__ seg,
    const float* __restrict__ sum_o, const float* __restrict__ sum_w,
    float* __restrict__ out)
{
  const long i0 = ((long)blockIdx.x * 256 + threadIdx.x) * 4;
  if (i0 >= N_ATOMS) return;
  const int4   s4 = *reinterpret_cast<const int4*>(seg + i0);
  const float4 o4 = *reinterpret_cast<const float4*>(outA + i0);
  const float4 w4 = *reinterpret_cast<const float4*>(outW + i0);
  const int   ss[4] = {s4.x, s4.y, s4.z, s4.w};
  const float oo[4] = {o4.x, o4.y, o4.z, o4.w};
  const float ww[4] = {w4.x, w4.y, w4.z, w4.w};
  float r[4];
  #pragma unroll
  for (int j = 0; j < 4; ++j) {
    const int s = ss[j];
    float sw = sum_w[s];
    sw = (sw == 0.f) ? 1.f : sw;
    const float corr = (0.f - sum_o[s]) / sw;
    r[j] = oo[j] + ww[j] * corr;
  }
  *reinterpret_cast<float4*>(out + i0) = make_float4(r[0], r[1], r[2], r[3]);
}

// ---------------------------------------------------------------------------
extern "C" void kernel_launch(void* const* d_in, const int* in_sizes, int n_in,
                              void* d_out, int out_size, void* d_ws, size_t ws_size,
                              hipStream_t stream)
{
  const float* hidden = (const float*)d_in[0];
  const int*   seg    = (const int*)d_in[1];
  const float* W1     = (const float*)d_in[2];
  const float* b1     = (const float*)d_in[3];
  const float* W2     = (const float*)d_in[4];
  const float* b2     = (const float*)d_in[5];
  const float* V1     = (const float*)d_in[6];
  const float* vb1    = (const float*)d_in[7];
  const float* V2     = (const float*)d_in[8];
  const float* vb2    = (const float*)d_in[9];

  char* ws = (char*)d_ws;
  float*          outA  = (float*)(ws + 0);          // 2,000,000 B
  float*          outW  = (float*)(ws + 2000000);    // 2,000,000 B
  float*          sum_o = (float*)(ws + 4000000);    //   100,000 B
  float*          sum_w = (float*)(ws + 4100000);    //   100,000 B
  unsigned short* W1s   = (unsigned short*)(ws + 4200000);  // 204,800 B
  unsigned short* V1s   = (unsigned short*)(ws + 4404800);  // 204,800 B
  float*          b1p   = (float*)(ws + 4609600);    // 1,280 B
  float*          vb1p  = (float*)(ws + 4610880);
  float*          W2p   = (float*)(ws + 4612160);
  float*          V2p   = (float*)(ws + 4613440);

  prep_kernel<<<1001, 256, 0, stream>>>(W1, V1, b1, vb1, W2, V2,
                                        W1s, V1s, b1p, vb1p, W2p, V2p, sum_o);

  const int nblk = (N_ATOMS + BA - 1) / BA;   // 3907
  fused_ffn<<<nblk, NTHR, 0, stream>>>(hidden, W1s, V1s, b1p, vb1p, W2p, V2p,
                                       b2, vb2, outA, outW);

  segsum_kernel<<<(N_ATOMS / 8 + 255) / 256, 256, 0, stream>>>(outA, outW, seg,
                                                               sum_o, sum_w);

  final_kernel<<<(N_ATOMS / 4 + 255) / 256, 256, 0, stream>>>(outA, outW, seg,
                                                              sum_o, sum_w,
                                                              (float*)d_out);
}